// Round 2
// baseline (736.681 us; speedup 1.0000x reference)
//
#include <hip/hip_runtime.h>
#include <hip/hip_bf16.h>

#define CAP 64          // max in-degree capacity per dst (incl self-loop); Poisson(~17) tail negligible
#define EPSBN 1e-5f
#define NEG_SLOPE 0.2f
#define NPARAM 24       // float param tensors: d_in[3..26]

static __device__ __forceinline__ float b2f(__hip_bfloat16 v) { return __bfloat162float(v); }
static __device__ __forceinline__ bool is_f32(const int* flagcnt) { return *flagcnt > 32; }

// ---------------- dtype probe: count huge-exponent bf16 interpretations ----------------
__global__ void k_detect(const unsigned short* __restrict__ raw, int* flagcnt) {
    int t = threadIdx.x;  // 256 threads, 1 block
    int c = 0;
    for (int i = t; i < 4096; i += 256) {
        int e = (raw[i] >> 7) & 0xFF;
        if (e >= 200) c++;  // |v| >= ~2^73 — never happens for N(0,1) bf16 data
    }
    atomicAdd(flagcnt, c);
}

// ---------------- dtype-aware converts ----------------
__global__ void k_cvt_x(const void* __restrict__ src, float* __restrict__ dst,
                        const int* flagcnt, int total) {
    bool f32 = is_f32(flagcnt);
    int i = blockIdx.x * blockDim.x + threadIdx.x;
    if (i < total)
        dst[i] = f32 ? ((const float*)src)[i] : b2f(((const __hip_bfloat16*)src)[i]);
}

struct CvtTab {
    const void* src[NPARAM];
    float* dst[NPARAM];
    int off[NPARAM + 1];
};

__global__ void k_cvt_params(CvtTab tab, const int* flagcnt, int total) {
    bool f32 = is_f32(flagcnt);
    for (int i = blockIdx.x * blockDim.x + threadIdx.x; i < total; i += gridDim.x * blockDim.x) {
        int j = 0;
        while (tab.off[j + 1] <= i) j++;
        int k = i - tab.off[j];
        tab.dst[j][k] = f32 ? ((const float*)tab.src[j])[k]
                            : b2f(((const __hip_bfloat16*)tab.src[j])[k]);
    }
}

// ---------------- graph build ----------------
__global__ void k_init_graph(int* cnt, int* adj, int n) {
    int i = blockIdx.x * blockDim.x + threadIdx.x;
    if (i < n) { cnt[i] = 1; adj[i * CAP] = i; }  // self-loop in slot 0
}

__global__ void k_fill_graph(const int* __restrict__ ei, int* cnt, int* adj, int E) {
    int e = blockIdx.x * blockDim.x + threadIdx.x;
    if (e < E) {
        int s = ei[e];
        int d = ei[E + e];
        int slot = atomicAdd(&cnt[d], 1);
        if (slot < CAP) adj[d * CAP + slot] = s;
    }
}

// ---------------- fp32 GEMM: C[M,F] = A[M,K](lda) @ B[K,F] ----------------
__global__ __launch_bounds__(256) void k_gemm(const float* __restrict__ A,
                                              const float* __restrict__ B,
                                              float* __restrict__ C,
                                              int M, int K, int F, int lda) {
    __shared__ float As[16][65];
    __shared__ float Bs[16][64];
    int t = threadIdx.x;
    int tx = t & 15, ty = t >> 4;
    int rowBase = blockIdx.x * 64;
    int colBase = blockIdx.y * 64;
    float acc[4][4] = {};
    for (int k0 = 0; k0 < K; k0 += 16) {
        #pragma unroll
        for (int i = 0; i < 4; i++) {
            int idx = t + 256 * i;
            int r = idx >> 4, c = idx & 15;
            int gr = rowBase + r;
            As[c][r] = (gr < M) ? A[(long)gr * lda + k0 + c] : 0.f;
        }
        #pragma unroll
        for (int i = 0; i < 4; i++) {
            int idx = t + 256 * i;
            int r = idx >> 6, c = idx & 63;
            Bs[r][c] = B[(long)(k0 + r) * F + colBase + c];
        }
        __syncthreads();
        #pragma unroll
        for (int kk = 0; kk < 16; kk++) {
            float a[4], b[4];
            #pragma unroll
            for (int i = 0; i < 4; i++) a[i] = As[kk][ty * 4 + i];
            #pragma unroll
            for (int j = 0; j < 4; j++) b[j] = Bs[kk][tx * 4 + j];
            #pragma unroll
            for (int i = 0; i < 4; i++)
                #pragma unroll
                for (int j = 0; j < 4; j++) acc[i][j] += a[i] * b[j];
        }
        __syncthreads();
    }
    #pragma unroll
    for (int i = 0; i < 4; i++) {
        int gr = rowBase + ty * 4 + i;
        if (gr < M) {
            #pragma unroll
            for (int j = 0; j < 4; j++)
                C[(long)gr * F + colBase + tx * 4 + j] = acc[i][j];
        }
    }
}

// ---------------- attention coefficients: es/ed [N,H], one wave per node ----------------
template <int F, int H>
__global__ void k_attn(const float* __restrict__ h,
                       const float* __restrict__ a_s,
                       const float* __restrict__ a_d,
                       float* __restrict__ es, float* __restrict__ ed, int n) {
    const int VPL = F / 64;
    const int LPH = 64 / H;
    int lane = threadIdx.x & 63;
    int node = (blockIdx.x * blockDim.x + threadIdx.x) >> 6;
    if (node >= n) return;
    float ps = 0.f, pd = 0.f;
    #pragma unroll
    for (int j = 0; j < VPL; j++) {
        float hv = h[(long)node * F + lane * VPL + j];
        ps += hv * a_s[lane * VPL + j];
        pd += hv * a_d[lane * VPL + j];
    }
    #pragma unroll
    for (int m = 1; m < LPH; m <<= 1) {
        ps += __shfl_xor(ps, m, 64);
        pd += __shfl_xor(pd, m, 64);
    }
    if ((lane & (LPH - 1)) == 0) {
        int head = lane / LPH;
        es[node * H + head] = ps;
        ed[node * H + head] = pd;
    }
}

// ---------------- attention aggregation: one wave per dst ----------------
template <int F, int H>
__global__ void k_agg(const float* __restrict__ h,
                      const float* __restrict__ es, const float* __restrict__ ed,
                      const int* __restrict__ cnt, const int* __restrict__ adj,
                      const float* __restrict__ bias,
                      float* __restrict__ out, int n) {
    const int VPL = F / 64;
    const int LPH = 64 / H;
    int lane = threadIdx.x & 63;
    int dst = (blockIdx.x * blockDim.x + threadIdx.x) >> 6;
    if (dst >= n) return;
    int hl = lane / LPH;
    float edc = ed[dst * H + hl];
    int deg = min(cnt[dst], CAP);
    const int* ap = adj + (long)dst * CAP;
    float m = -1e30f;
    for (int i = 0; i < deg; i++) {
        int s = ap[i];
        float e = es[s * H + hl] + edc;
        e = e > 0.f ? e : NEG_SLOPE * e;
        m = fmaxf(m, e);
    }
    float z = 0.f;
    float acc[VPL] = {};
    for (int i = 0; i < deg; i++) {
        int s = ap[i];
        float e = es[s * H + hl] + edc;
        e = e > 0.f ? e : NEG_SLOPE * e;
        float w = __expf(e - m);
        z += w;
        const float* hp = h + (long)s * F + lane * VPL;
        if (VPL == 4) {
            float4 hv = *(const float4*)hp;
            acc[0] += w * hv.x; acc[1] += w * hv.y; acc[2] += w * hv.z; acc[3] += w * hv.w;
        } else {
            float2 hv = *(const float2*)hp;
            acc[0] += w * hv.x; acc[1] += w * hv.y;
        }
    }
    float invz = 1.f / z;
    #pragma unroll
    for (int j = 0; j < VPL; j++)
        out[(long)dst * F + lane * VPL + j] = acc[j] * invz + bias[lane * VPL + j];
}

// ---------------- batchnorm ----------------
template <int F>
__global__ void k_bnstats(const float* __restrict__ x, float* bnsum, float* bnsq, int n) {
    int t = threadIdx.x;  // blockDim == F
    float s = 0.f, q = 0.f;
    for (int r = blockIdx.x; r < n; r += gridDim.x) {
        float v = x[(long)r * F + t];
        s += v; q += v * v;
    }
    atomicAdd(&bnsum[t], s);
    atomicAdd(&bnsq[t], q);
}

template <int F>
__global__ void k_bnapply(float* __restrict__ x,
                          const float* __restrict__ bnsum, const float* __restrict__ bnsq,
                          const float* __restrict__ gamma, const float* __restrict__ beta,
                          int n) {
    int idx = blockIdx.x * blockDim.x + threadIdx.x;
    if (idx >= n * F) return;
    int f = idx & (F - 1);
    float invN = 1.f / (float)n;
    float mu = bnsum[f] * invN;
    float var = bnsq[f] * invN - mu * mu;
    float v = (x[idx] - mu) * rsqrtf(var + EPSBN) * gamma[f] + beta[f];
    x[idx] = v > 0.f ? v : 0.f;
}

// ---------------- graph mean-pool ----------------
__global__ void k_pool(const float* __restrict__ x, const int* __restrict__ batch,
                       float* featsum, int* gcnt, int n) {
    int lane = threadIdx.x & 63;
    int node = (blockIdx.x * blockDim.x + threadIdx.x) >> 6;
    if (node >= n) return;
    int g = batch[node];
    float2 v = *(const float2*)(x + (long)node * 128 + lane * 2);
    atomicAdd(&featsum[g * 128 + lane * 2], v.x);
    atomicAdd(&featsum[g * 128 + lane * 2 + 1], v.y);
    if (lane == 0) atomicAdd(&gcnt[g], 1);
}

// ---------------- heads ----------------
__global__ void k_head(const float* __restrict__ featsum, const int* __restrict__ gcnt,
                       const float* __restrict__ clfW, const float* __restrict__ clfb,
                       const float* __restrict__ dW1, const float* __restrict__ db1,
                       const float* __restrict__ dW2, const float* __restrict__ db2,
                       void* __restrict__ out, const int* flagcnt, int G) {
    __shared__ float feat[128];
    __shared__ float dh[64];
    bool f32o = is_f32(flagcnt);
    float* of = (float*)out;
    __hip_bfloat16* ob = (__hip_bfloat16*)out;
    int g = blockIdx.x, t = threadIdx.x;  // 128 threads
    float c = fmaxf((float)gcnt[g], 1.f);
    float fv = featsum[g * 128 + t] / c;
    feat[t] = fv;
    int fidx = G * 10 + G * 2 + g * 128 + t;
    if (f32o) of[fidx] = fv; else ob[fidx] = __float2bfloat16(fv);
    __syncthreads();
    if (t < 10) {
        float a = clfb[t];
        for (int k = 0; k < 128; k++) a += feat[k] * clfW[k * 10 + t];
        int idx = g * 10 + t;
        if (f32o) of[idx] = a; else ob[idx] = __float2bfloat16(a);
    }
    if (t < 64) {
        float a = db1[t];
        for (int k = 0; k < 128; k++) a += feat[k] * dW1[k * 64 + t];
        dh[t] = a > 0.f ? a : 0.f;
    }
    __syncthreads();
    if (t < 2) {
        float a = db2[t];
        for (int k = 0; k < 64; k++) a += dh[k] * dW2[k * 2 + t];
        int idx = G * 10 + g * 2 + t;
        if (f32o) of[idx] = a; else ob[idx] = __float2bfloat16(a);
    }
}

// ---------------- launch ----------------
extern "C" void kernel_launch(void* const* d_in, const int* in_sizes, int n_in,
                              void* d_out, int out_size, void* d_ws, size_t ws_size,
                              hipStream_t stream) {
    const void* x_in = d_in[0];
    const int* ei    = (const int*)d_in[1];
    const int* batch = (const int*)d_in[2];
    const int N = in_sizes[2];
    const int E = in_sizes[1] / 2;
    const int G = 64;

    // workspace layout (256B aligned chunks)
    char* ws = (char*)d_ws;
    size_t off = 0;
    auto alloc = [&](size_t bytes) {
        void* p = ws + off;
        off += (bytes + 255) & ~(size_t)255;
        return p;
    };
    int*   flagcnt = (int*)alloc(256);
    int*   cnt     = (int*)alloc((size_t)N * 4);
    int*   adj     = (int*)alloc((size_t)N * CAP * 4);
    float* xbuf    = (float*)alloc((size_t)N * 256 * 4);
    float* hbuf    = (float*)alloc((size_t)N * 256 * 4);
    float* es      = (float*)alloc((size_t)N * 4 * 4);
    float* ed      = (float*)alloc((size_t)N * 4 * 4);
    float* bnsum   = (float*)alloc(256 * 4 + 256 * 4);
    float* bnsq    = bnsum + 256;
    float* featsum = (float*)alloc((size_t)G * 128 * 4 + (size_t)G * 4);
    int*   gcnt    = (int*)(featsum + G * 128);

    // fp32 copies of the 24 float param tensors (d_in[3..26])
    CvtTab tab;
    float* pp[NPARAM];
    int ptot = 0;
    for (int j = 0; j < NPARAM; j++) {
        int cnt_j = in_sizes[3 + j];
        pp[j] = (float*)alloc((size_t)cnt_j * 4);
        tab.src[j] = d_in[3 + j];
        tab.dst[j] = pp[j];
        tab.off[j] = ptot;
        ptot += cnt_j;
    }
    tab.off[NPARAM] = ptot;
    float *Wf0 = pp[0], *asf0 = pp[1], *adf0 = pp[2], *bf0 = pp[3], *gf0 = pp[4], *bef0 = pp[5];
    float *Wf1 = pp[6], *asf1 = pp[7], *adf1 = pp[8], *bf1 = pp[9], *gf1 = pp[10], *bef1 = pp[11];
    float *Wf2 = pp[12], *asf2 = pp[13], *adf2 = pp[14], *bf2 = pp[15], *gf2 = pp[16], *bef2 = pp[17];
    float *clfWf = pp[18], *clfbf = pp[19], *dW1f = pp[20], *db1f = pp[21], *dW2f = pp[22], *db2f = pp[23];

    const int TPB = 256;
    int wgrid = (N + 3) / 4;  // one wave per node

    // dtype probe + converts
    hipMemsetAsync(flagcnt, 0, 4, stream);
    k_detect<<<1, 256, 0, stream>>>((const unsigned short*)x_in, flagcnt);
    k_cvt_x<<<(N * 128 + TPB - 1) / TPB, TPB, 0, stream>>>(x_in, xbuf, flagcnt, N * 128);
    k_cvt_params<<<(ptot + TPB - 1) / TPB, TPB, 0, stream>>>(tab, flagcnt, ptot);

    // graph build
    k_init_graph<<<(N + TPB - 1) / TPB, TPB, 0, stream>>>(cnt, adj, N);
    k_fill_graph<<<(E + TPB - 1) / TPB, TPB, 0, stream>>>(ei, cnt, adj, E);

    // ---- layer 0: K=128 -> F=256, H=4, D=64 ----
    {
        dim3 grid((N + 63) / 64, 256 / 64);
        k_gemm<<<grid, 256, 0, stream>>>(xbuf, Wf0, hbuf, N, 128, 256, 128);
        k_attn<256, 4><<<wgrid, 256, 0, stream>>>(hbuf, asf0, adf0, es, ed, N);
        k_agg<256, 4><<<wgrid, 256, 0, stream>>>(hbuf, es, ed, cnt, adj, bf0, xbuf, N);
        hipMemsetAsync(bnsum, 0, 2048, stream);
        k_bnstats<256><<<160, 256, 0, stream>>>(xbuf, bnsum, bnsq, N);
        k_bnapply<256><<<(N * 256 + TPB - 1) / TPB, TPB, 0, stream>>>(xbuf, bnsum, bnsq, gf0, bef0, N);
    }
    // ---- layer 1: K=256 -> F=256, H=4, D=64 ----
    {
        dim3 grid((N + 63) / 64, 256 / 64);
        k_gemm<<<grid, 256, 0, stream>>>(xbuf, Wf1, hbuf, N, 256, 256, 256);
        k_attn<256, 4><<<wgrid, 256, 0, stream>>>(hbuf, asf1, adf1, es, ed, N);
        k_agg<256, 4><<<wgrid, 256, 0, stream>>>(hbuf, es, ed, cnt, adj, bf1, xbuf, N);
        hipMemsetAsync(bnsum, 0, 2048, stream);
        k_bnstats<256><<<160, 256, 0, stream>>>(xbuf, bnsum, bnsq, N);
        k_bnapply<256><<<(N * 256 + TPB - 1) / TPB, TPB, 0, stream>>>(xbuf, bnsum, bnsq, gf1, bef1, N);
    }
    // ---- layer 2: K=256 -> F=128, H=1, D=128 ----
    {
        dim3 grid((N + 63) / 64, 128 / 64);
        k_gemm<<<grid, 256, 0, stream>>>(xbuf, Wf2, hbuf, N, 256, 128, 256);
        k_attn<128, 1><<<wgrid, 256, 0, stream>>>(hbuf, asf2, adf2, es, ed, N);
        k_agg<128, 1><<<wgrid, 256, 0, stream>>>(hbuf, es, ed, cnt, adj, bf2, xbuf, N);
        hipMemsetAsync(bnsum, 0, 2048, stream);
        k_bnstats<128><<<160, 128, 0, stream>>>(xbuf, bnsum, bnsq, N);
        k_bnapply<128><<<(N * 128 + TPB - 1) / TPB, TPB, 0, stream>>>(xbuf, bnsum, bnsq, gf2, bef2, N);
    }

    // ---- pooling + heads ----
    hipMemsetAsync(featsum, 0, (size_t)G * 128 * 4 + (size_t)G * 4, stream);
    k_pool<<<wgrid, 256, 0, stream>>>(xbuf, batch, featsum, gcnt, N);
    k_head<<<G, 128, 0, stream>>>(featsum, gcnt, clfWf, clfbf, dW1f, db1f, dW2f, db2f,
                                  d_out, flagcnt, G);
}

// Round 3
// 622.638 us; speedup vs baseline: 1.1832x; 1.1832x over previous
//
#include <hip/hip_runtime.h>
#include <hip/hip_bf16.h>

#define CAP 64          // max in-degree capacity per dst (incl self-loop); Poisson(~17) tail negligible
#define EPSBN 1e-5f
#define NEG_SLOPE 0.2f
#define NPARAM 24       // float param tensors: d_in[3..26]
#define POOL_SPLIT 4    // blocks per graph in pooling

static __device__ __forceinline__ float b2f(__hip_bfloat16 v) { return __bfloat162float(v); }
static __device__ __forceinline__ bool is_f32(const int* flagcnt) { return *flagcnt > 32; }

// ---------------- dtype probe: count huge-exponent bf16 interpretations ----------------
__global__ void k_detect(const unsigned short* __restrict__ raw, int* flagcnt) {
    int t = threadIdx.x;  // 256 threads, 1 block
    int c = 0;
    for (int i = t; i < 4096; i += 256) {
        int e = (raw[i] >> 7) & 0xFF;
        if (e >= 200) c++;  // |v| >= ~2^73 — never happens for N(0,1) bf16 data
    }
    atomicAdd(flagcnt, c);
}

// ---------------- dtype-aware converts ----------------
__global__ void k_cvt_x(const void* __restrict__ src, float* __restrict__ dst,
                        const int* flagcnt, int total) {
    bool f32 = is_f32(flagcnt);
    int i = blockIdx.x * blockDim.x + threadIdx.x;
    if (i < total)
        dst[i] = f32 ? ((const float*)src)[i] : b2f(((const __hip_bfloat16*)src)[i]);
}

struct CvtTab {
    const void* src[NPARAM];
    float* dst[NPARAM];
    int off[NPARAM + 1];
};

__global__ void k_cvt_params(CvtTab tab, const int* flagcnt, int total) {
    bool f32 = is_f32(flagcnt);
    for (int i = blockIdx.x * blockDim.x + threadIdx.x; i < total; i += gridDim.x * blockDim.x) {
        int j = 0;
        while (tab.off[j + 1] <= i) j++;
        int k = i - tab.off[j];
        tab.dst[j][k] = f32 ? ((const float*)tab.src[j])[k]
                            : b2f(((const __hip_bfloat16*)tab.src[j])[k]);
    }
}

// ---------------- graph build ----------------
__global__ void k_init_graph(int* cnt, int* adj, int n) {
    int i = blockIdx.x * blockDim.x + threadIdx.x;
    if (i < n) { cnt[i] = 1; adj[i * CAP] = i; }  // self-loop in slot 0
}

__global__ void k_fill_graph(const int* __restrict__ ei, int* cnt, int* adj, int E) {
    int e = blockIdx.x * blockDim.x + threadIdx.x;
    if (e < E) {
        int s = ei[e];
        int d = ei[E + e];
        int slot = atomicAdd(&cnt[d], 1);
        if (slot < CAP) adj[d * CAP + slot] = s;
    }
}

// ---------------- fp32 GEMM: C[M,F] = A[M,K](lda) @ B[K,F] ----------------
__global__ __launch_bounds__(256) void k_gemm(const float* __restrict__ A,
                                              const float* __restrict__ B,
                                              float* __restrict__ C,
                                              int M, int K, int F, int lda) {
    __shared__ float As[16][65];
    __shared__ float Bs[16][64];
    int t = threadIdx.x;
    int tx = t & 15, ty = t >> 4;
    int rowBase = blockIdx.x * 64;
    int colBase = blockIdx.y * 64;
    float acc[4][4] = {};
    for (int k0 = 0; k0 < K; k0 += 16) {
        #pragma unroll
        for (int i = 0; i < 4; i++) {
            int idx = t + 256 * i;
            int r = idx >> 4, c = idx & 15;
            int gr = rowBase + r;
            As[c][r] = (gr < M) ? A[(long)gr * lda + k0 + c] : 0.f;
        }
        #pragma unroll
        for (int i = 0; i < 4; i++) {
            int idx = t + 256 * i;
            int r = idx >> 6, c = idx & 63;
            Bs[r][c] = B[(long)(k0 + r) * F + colBase + c];
        }
        __syncthreads();
        #pragma unroll
        for (int kk = 0; kk < 16; kk++) {
            float a[4], b[4];
            #pragma unroll
            for (int i = 0; i < 4; i++) a[i] = As[kk][ty * 4 + i];
            #pragma unroll
            for (int j = 0; j < 4; j++) b[j] = Bs[kk][tx * 4 + j];
            #pragma unroll
            for (int i = 0; i < 4; i++)
                #pragma unroll
                for (int j = 0; j < 4; j++) acc[i][j] += a[i] * b[j];
        }
        __syncthreads();
    }
    #pragma unroll
    for (int i = 0; i < 4; i++) {
        int gr = rowBase + ty * 4 + i;
        if (gr < M) {
            #pragma unroll
            for (int j = 0; j < 4; j++)
                C[(long)gr * F + colBase + tx * 4 + j] = acc[i][j];
        }
    }
}

// ---------------- attention coefficients: es/ed [N,H], one wave per node ----------------
template <int F, int H>
__global__ void k_attn(const float* __restrict__ h,
                       const float* __restrict__ a_s,
                       const float* __restrict__ a_d,
                       float* __restrict__ es, float* __restrict__ ed, int n) {
    const int VPL = F / 64;
    const int LPH = 64 / H;
    int lane = threadIdx.x & 63;
    int node = (blockIdx.x * blockDim.x + threadIdx.x) >> 6;
    if (node >= n) return;
    float ps = 0.f, pd = 0.f;
    #pragma unroll
    for (int j = 0; j < VPL; j++) {
        float hv = h[(long)node * F + lane * VPL + j];
        ps += hv * a_s[lane * VPL + j];
        pd += hv * a_d[lane * VPL + j];
    }
    #pragma unroll
    for (int m = 1; m < LPH; m <<= 1) {
        ps += __shfl_xor(ps, m, 64);
        pd += __shfl_xor(pd, m, 64);
    }
    if ((lane & (LPH - 1)) == 0) {
        int head = lane / LPH;
        es[node * H + head] = ps;
        ed[node * H + head] = pd;
    }
}

// ---------------- attention aggregation: one wave per dst ----------------
template <int F, int H>
__global__ void k_agg(const float* __restrict__ h,
                      const float* __restrict__ es, const float* __restrict__ ed,
                      const int* __restrict__ cnt, const int* __restrict__ adj,
                      const float* __restrict__ bias,
                      float* __restrict__ out, int n) {
    const int VPL = F / 64;
    const int LPH = 64 / H;
    int lane = threadIdx.x & 63;
    int dst = (blockIdx.x * blockDim.x + threadIdx.x) >> 6;
    if (dst >= n) return;
    int hl = lane / LPH;
    float edc = ed[dst * H + hl];
    int deg = min(cnt[dst], CAP);
    const int* ap = adj + (long)dst * CAP;
    float m = -1e30f;
    for (int i = 0; i < deg; i++) {
        int s = ap[i];
        float e = es[s * H + hl] + edc;
        e = e > 0.f ? e : NEG_SLOPE * e;
        m = fmaxf(m, e);
    }
    float z = 0.f;
    float acc[VPL] = {};
    for (int i = 0; i < deg; i++) {
        int s = ap[i];
        float e = es[s * H + hl] + edc;
        e = e > 0.f ? e : NEG_SLOPE * e;
        float w = __expf(e - m);
        z += w;
        const float* hp = h + (long)s * F + lane * VPL;
        if (VPL == 4) {
            float4 hv = *(const float4*)hp;
            acc[0] += w * hv.x; acc[1] += w * hv.y; acc[2] += w * hv.z; acc[3] += w * hv.w;
        } else {
            float2 hv = *(const float2*)hp;
            acc[0] += w * hv.x; acc[1] += w * hv.y;
        }
    }
    float invz = 1.f / z;
    #pragma unroll
    for (int j = 0; j < VPL; j++)
        out[(long)dst * F + lane * VPL + j] = acc[j] * invz + bias[lane * VPL + j];
}

// ---------------- batchnorm ----------------
template <int F>
__global__ void k_bnstats(const float* __restrict__ x, float* bnsum, float* bnsq, int n) {
    int t = threadIdx.x;  // blockDim == F
    float s = 0.f, q = 0.f;
    for (int r = blockIdx.x; r < n; r += gridDim.x) {
        float v = x[(long)r * F + t];
        s += v; q += v * v;
    }
    atomicAdd(&bnsum[t], s);
    atomicAdd(&bnsq[t], q);
}

template <int F>
__global__ void k_bnapply(float* __restrict__ x,
                          const float* __restrict__ bnsum, const float* __restrict__ bnsq,
                          const float* __restrict__ gamma, const float* __restrict__ beta,
                          int n) {
    int idx = blockIdx.x * blockDim.x + threadIdx.x;
    if (idx >= n * F) return;
    int f = idx & (F - 1);
    float invN = 1.f / (float)n;
    float mu = bnsum[f] * invN;
    float var = bnsq[f] * invN - mu * mu;
    float v = (x[idx] - mu) * rsqrtf(var + EPSBN) * gamma[f] + beta[f];
    x[idx] = v > 0.f ? v : 0.f;
}

// ---------------- graph mean-pool: batch is SORTED -> segmented reduction ----------------
static __device__ __forceinline__ int lower_bound_i(const int* __restrict__ a, int n, int v) {
    int lo = 0, hi = n;
    while (lo < hi) { int mid = (lo + hi) >> 1; if (a[mid] < v) lo = mid + 1; else hi = mid; }
    return lo;
}

// grid = G * POOL_SPLIT blocks, 256 threads. One atomicAdd per (block, feature).
__global__ __launch_bounds__(256) void k_pool2(const float* __restrict__ x,
                                               const int* __restrict__ batch,
                                               float* __restrict__ featsum,
                                               int* __restrict__ gcnt, int n) {
    __shared__ float sm[256];
    int g = blockIdx.x / POOL_SPLIT;
    int part = blockIdx.x % POOL_SPLIT;
    int t = threadIdx.x;
    int lo = lower_bound_i(batch, n, g);
    int hi = lower_bound_i(batch, n, g + 1);
    int f = t & 127;
    int phase = t >> 7;  // 0/1: two rows in flight
    float acc = 0.f;
    for (int r = lo + part * 2 + phase; r < hi; r += POOL_SPLIT * 2)
        acc += x[(long)r * 128 + f];
    sm[t] = acc;
    __syncthreads();
    if (t < 128) {
        float s = sm[t] + sm[t + 128];
        atomicAdd(&featsum[g * 128 + t], s);
    }
    if (t == 0 && part == 0) gcnt[g] = hi - lo;
}

// ---------------- heads ----------------
__global__ void k_head(const float* __restrict__ featsum, const int* __restrict__ gcnt,
                       const float* __restrict__ clfW, const float* __restrict__ clfb,
                       const float* __restrict__ dW1, const float* __restrict__ db1,
                       const float* __restrict__ dW2, const float* __restrict__ db2,
                       void* __restrict__ out, const int* flagcnt, int G) {
    __shared__ float feat[128];
    __shared__ float dh[64];
    bool f32o = is_f32(flagcnt);
    float* of = (float*)out;
    __hip_bfloat16* ob = (__hip_bfloat16*)out;
    int g = blockIdx.x, t = threadIdx.x;  // 128 threads
    float c = fmaxf((float)gcnt[g], 1.f);
    float fv = featsum[g * 128 + t] / c;
    feat[t] = fv;
    int fidx = G * 10 + G * 2 + g * 128 + t;
    if (f32o) of[fidx] = fv; else ob[fidx] = __float2bfloat16(fv);
    __syncthreads();
    if (t < 10) {
        float a = clfb[t];
        for (int k = 0; k < 128; k++) a += feat[k] * clfW[k * 10 + t];
        int idx = g * 10 + t;
        if (f32o) of[idx] = a; else ob[idx] = __float2bfloat16(a);
    }
    if (t < 64) {
        float a = db1[t];
        for (int k = 0; k < 128; k++) a += feat[k] * dW1[k * 64 + t];
        dh[t] = a > 0.f ? a : 0.f;
    }
    __syncthreads();
    if (t < 2) {
        float a = db2[t];
        for (int k = 0; k < 64; k++) a += dh[k] * dW2[k * 2 + t];
        int idx = G * 10 + g * 2 + t;
        if (f32o) of[idx] = a; else ob[idx] = __float2bfloat16(a);
    }
}

// ---------------- launch ----------------
extern "C" void kernel_launch(void* const* d_in, const int* in_sizes, int n_in,
                              void* d_out, int out_size, void* d_ws, size_t ws_size,
                              hipStream_t stream) {
    const void* x_in = d_in[0];
    const int* ei    = (const int*)d_in[1];
    const int* batch = (const int*)d_in[2];
    const int N = in_sizes[2];
    const int E = in_sizes[1] / 2;
    const int G = 64;

    // workspace layout (256B aligned chunks)
    char* ws = (char*)d_ws;
    size_t off = 0;
    auto alloc = [&](size_t bytes) {
        void* p = ws + off;
        off += (bytes + 255) & ~(size_t)255;
        return p;
    };
    int*   flagcnt = (int*)alloc(256);
    int*   cnt     = (int*)alloc((size_t)N * 4);
    int*   adj     = (int*)alloc((size_t)N * CAP * 4);
    float* xbuf    = (float*)alloc((size_t)N * 256 * 4);
    float* hbuf    = (float*)alloc((size_t)N * 256 * 4);
    float* es      = (float*)alloc((size_t)N * 4 * 4);
    float* ed      = (float*)alloc((size_t)N * 4 * 4);
    float* bnsum   = (float*)alloc(256 * 4 + 256 * 4);
    float* bnsq    = bnsum + 256;
    float* featsum = (float*)alloc((size_t)G * 128 * 4 + (size_t)G * 4);
    int*   gcnt    = (int*)(featsum + G * 128);

    // fp32 copies of the 24 float param tensors (d_in[3..26])
    CvtTab tab;
    float* pp[NPARAM];
    int ptot = 0;
    for (int j = 0; j < NPARAM; j++) {
        int cnt_j = in_sizes[3 + j];
        pp[j] = (float*)alloc((size_t)cnt_j * 4);
        tab.src[j] = d_in[3 + j];
        tab.dst[j] = pp[j];
        tab.off[j] = ptot;
        ptot += cnt_j;
    }
    tab.off[NPARAM] = ptot;
    float *Wf0 = pp[0], *asf0 = pp[1], *adf0 = pp[2], *bf0 = pp[3], *gf0 = pp[4], *bef0 = pp[5];
    float *Wf1 = pp[6], *asf1 = pp[7], *adf1 = pp[8], *bf1 = pp[9], *gf1 = pp[10], *bef1 = pp[11];
    float *Wf2 = pp[12], *asf2 = pp[13], *adf2 = pp[14], *bf2 = pp[15], *gf2 = pp[16], *bef2 = pp[17];
    float *clfWf = pp[18], *clfbf = pp[19], *dW1f = pp[20], *db1f = pp[21], *dW2f = pp[22], *db2f = pp[23];

    const int TPB = 256;
    int wgrid = (N + 3) / 4;  // one wave per node

    // dtype probe + converts
    hipMemsetAsync(flagcnt, 0, 4, stream);
    k_detect<<<1, 256, 0, stream>>>((const unsigned short*)x_in, flagcnt);
    k_cvt_x<<<(N * 128 + TPB - 1) / TPB, TPB, 0, stream>>>(x_in, xbuf, flagcnt, N * 128);
    k_cvt_params<<<(ptot + TPB - 1) / TPB, TPB, 0, stream>>>(tab, flagcnt, ptot);

    // graph build
    k_init_graph<<<(N + TPB - 1) / TPB, TPB, 0, stream>>>(cnt, adj, N);
    k_fill_graph<<<(E + TPB - 1) / TPB, TPB, 0, stream>>>(ei, cnt, adj, E);

    // ---- layer 0: K=128 -> F=256, H=4, D=64 ----
    {
        dim3 grid((N + 63) / 64, 256 / 64);
        k_gemm<<<grid, 256, 0, stream>>>(xbuf, Wf0, hbuf, N, 128, 256, 128);
        k_attn<256, 4><<<wgrid, 256, 0, stream>>>(hbuf, asf0, adf0, es, ed, N);
        k_agg<256, 4><<<wgrid, 256, 0, stream>>>(hbuf, es, ed, cnt, adj, bf0, xbuf, N);
        hipMemsetAsync(bnsum, 0, 2048, stream);
        k_bnstats<256><<<160, 256, 0, stream>>>(xbuf, bnsum, bnsq, N);
        k_bnapply<256><<<(N * 256 + TPB - 1) / TPB, TPB, 0, stream>>>(xbuf, bnsum, bnsq, gf0, bef0, N);
    }
    // ---- layer 1: K=256 -> F=256, H=4, D=64 ----
    {
        dim3 grid((N + 63) / 64, 256 / 64);
        k_gemm<<<grid, 256, 0, stream>>>(xbuf, Wf1, hbuf, N, 256, 256, 256);
        k_attn<256, 4><<<wgrid, 256, 0, stream>>>(hbuf, asf1, adf1, es, ed, N);
        k_agg<256, 4><<<wgrid, 256, 0, stream>>>(hbuf, es, ed, cnt, adj, bf1, xbuf, N);
        hipMemsetAsync(bnsum, 0, 2048, stream);
        k_bnstats<256><<<160, 256, 0, stream>>>(xbuf, bnsum, bnsq, N);
        k_bnapply<256><<<(N * 256 + TPB - 1) / TPB, TPB, 0, stream>>>(xbuf, bnsum, bnsq, gf1, bef1, N);
    }
    // ---- layer 2: K=256 -> F=128, H=1, D=128 ----
    {
        dim3 grid((N + 63) / 64, 128 / 64);
        k_gemm<<<grid, 256, 0, stream>>>(xbuf, Wf2, hbuf, N, 256, 128, 256);
        k_attn<128, 1><<<wgrid, 256, 0, stream>>>(hbuf, asf2, adf2, es, ed, N);
        k_agg<128, 1><<<wgrid, 256, 0, stream>>>(hbuf, es, ed, cnt, adj, bf2, xbuf, N);
        hipMemsetAsync(bnsum, 0, 2048, stream);
        k_bnstats<128><<<160, 128, 0, stream>>>(xbuf, bnsum, bnsq, N);
        k_bnapply<128><<<(N * 128 + TPB - 1) / TPB, TPB, 0, stream>>>(xbuf, bnsum, bnsq, gf2, bef2, N);
    }

    // ---- pooling + heads ----
    hipMemsetAsync(featsum, 0, (size_t)G * 128 * 4 + (size_t)G * 4, stream);
    k_pool2<<<G * POOL_SPLIT, 256, 0, stream>>>(xbuf, batch, featsum, gcnt, N);
    k_head<<<G, 128, 0, stream>>>(featsum, gcnt, clfWf, clfbf, dW1f, db1f, dW2f, db2f,
                                  d_out, flagcnt, G);
}

// Round 4
// 602.966 us; speedup vs baseline: 1.2218x; 1.0326x over previous
//
#include <hip/hip_runtime.h>
#include <hip/hip_bf16.h>

#define CAP 64          // max in-degree capacity per dst (incl self-loop); Poisson(~17) tail negligible
#define EPSBN 1e-5f
#define NEG_SLOPE 0.2f
#define NPARAM 24       // float param tensors: d_in[3..26]
#define POOL_SPLIT 4    // blocks per graph in pooling

static __device__ __forceinline__ float b2f(__hip_bfloat16 v) { return __bfloat162float(v); }
static __device__ __forceinline__ float u2f(unsigned short u) {  // bf16 bits -> float
    return __uint_as_float(((unsigned int)u) << 16);
}
static __device__ __forceinline__ unsigned short f2b_rne(float f) {  // float -> bf16 bits, RNE
    unsigned int u = __float_as_uint(f);
    u += 0x7FFF + ((u >> 16) & 1);
    return (unsigned short)(u >> 16);
}
static __device__ __forceinline__ bool is_f32(const int* flagcnt) { return *flagcnt > 32; }

// ---------------- dtype probe: count huge-exponent bf16 interpretations ----------------
__global__ void k_detect(const unsigned short* __restrict__ raw, int* flagcnt) {
    int t = threadIdx.x;  // 256 threads, 1 block
    int c = 0;
    for (int i = t; i < 4096; i += 256) {
        int e = (raw[i] >> 7) & 0xFF;
        if (e >= 200) c++;  // |v| >= ~2^73 — never happens for N(0,1) bf16 data
    }
    atomicAdd(flagcnt, c);
}

// ---------------- dtype-aware converts ----------------
__global__ void k_cvt_x(const void* __restrict__ src, float* __restrict__ dst,
                        const int* flagcnt, int total) {
    bool f32 = is_f32(flagcnt);
    int i = blockIdx.x * blockDim.x + threadIdx.x;
    if (i < total)
        dst[i] = f32 ? ((const float*)src)[i] : b2f(((const __hip_bfloat16*)src)[i]);
}

struct CvtTab {
    const void* src[NPARAM];
    float* dst[NPARAM];
    int off[NPARAM + 1];
};

__global__ void k_cvt_params(CvtTab tab, const int* flagcnt, int total) {
    bool f32 = is_f32(flagcnt);
    for (int i = blockIdx.x * blockDim.x + threadIdx.x; i < total; i += gridDim.x * blockDim.x) {
        int j = 0;
        while (tab.off[j + 1] <= i) j++;
        int k = i - tab.off[j];
        tab.dst[j][k] = f32 ? ((const float*)tab.src[j])[k]
                            : b2f(((const __hip_bfloat16*)tab.src[j])[k]);
    }
}

// ---------------- graph build ----------------
__global__ void k_init_graph(int* cnt, int* adj, int n) {
    int i = blockIdx.x * blockDim.x + threadIdx.x;
    if (i < n) { cnt[i] = 1; adj[i * CAP] = i; }  // self-loop in slot 0
}

__global__ void k_fill_graph(const int* __restrict__ ei, int* cnt, int* adj, int E) {
    int e = blockIdx.x * blockDim.x + threadIdx.x;
    if (e < E) {
        int s = ei[e];
        int d = ei[E + e];
        int slot = atomicAdd(&cnt[d], 1);
        if (slot < CAP) adj[d * CAP + slot] = s;
    }
}

// ---------------- fp32 GEMM -> bf16 C: C[M,F] = A[M,K](lda) @ B[K,F] ----------------
__global__ __launch_bounds__(256) void k_gemm(const float* __restrict__ A,
                                              const float* __restrict__ B,
                                              unsigned short* __restrict__ C,
                                              int M, int K, int F, int lda) {
    __shared__ float As[16][65];
    __shared__ float Bs[16][64];
    int t = threadIdx.x;
    int tx = t & 15, ty = t >> 4;
    int rowBase = blockIdx.x * 64;
    int colBase = blockIdx.y * 64;
    float acc[4][4] = {};
    for (int k0 = 0; k0 < K; k0 += 16) {
        #pragma unroll
        for (int i = 0; i < 4; i++) {
            int idx = t + 256 * i;
            int r = idx >> 4, c = idx & 15;
            int gr = rowBase + r;
            As[c][r] = (gr < M) ? A[(long)gr * lda + k0 + c] : 0.f;
        }
        #pragma unroll
        for (int i = 0; i < 4; i++) {
            int idx = t + 256 * i;
            int r = idx >> 6, c = idx & 63;
            Bs[r][c] = B[(long)(k0 + r) * F + colBase + c];
        }
        __syncthreads();
        #pragma unroll
        for (int kk = 0; kk < 16; kk++) {
            float a[4], b[4];
            #pragma unroll
            for (int i = 0; i < 4; i++) a[i] = As[kk][ty * 4 + i];
            #pragma unroll
            for (int j = 0; j < 4; j++) b[j] = Bs[kk][tx * 4 + j];
            #pragma unroll
            for (int i = 0; i < 4; i++)
                #pragma unroll
                for (int j = 0; j < 4; j++) acc[i][j] += a[i] * b[j];
        }
        __syncthreads();
    }
    #pragma unroll
    for (int i = 0; i < 4; i++) {
        int gr = rowBase + ty * 4 + i;
        if (gr < M) {
            ushort4 pk;
            pk.x = f2b_rne(acc[i][0]); pk.y = f2b_rne(acc[i][1]);
            pk.z = f2b_rne(acc[i][2]); pk.w = f2b_rne(acc[i][3]);
            *(ushort4*)(C + (long)gr * F + colBase + tx * 4) = pk;
        }
    }
}

// ---------------- attention coefficients: es/ed [N,H], one wave per node ----------------
template <int F, int H>
__global__ void k_attn(const unsigned short* __restrict__ h,
                       const float* __restrict__ a_s,
                       const float* __restrict__ a_d,
                       float* __restrict__ es, float* __restrict__ ed, int n) {
    const int VPL = F / 64;
    const int LPH = 64 / H;
    int lane = threadIdx.x & 63;
    int node = (blockIdx.x * blockDim.x + threadIdx.x) >> 6;
    if (node >= n) return;
    float hv[VPL];
    const unsigned short* hp = h + (long)node * F + lane * VPL;
    if (VPL == 4) {
        ushort4 p = *(const ushort4*)hp;
        hv[0] = u2f(p.x); hv[1] = u2f(p.y); hv[2] = u2f(p.z); hv[3] = u2f(p.w);
    } else {
        ushort2 p = *(const ushort2*)hp;
        hv[0] = u2f(p.x); hv[1] = u2f(p.y);
    }
    float ps = 0.f, pd = 0.f;
    #pragma unroll
    for (int j = 0; j < VPL; j++) {
        ps += hv[j] * a_s[lane * VPL + j];
        pd += hv[j] * a_d[lane * VPL + j];
    }
    #pragma unroll
    for (int m = 1; m < LPH; m <<= 1) {
        ps += __shfl_xor(ps, m, 64);
        pd += __shfl_xor(pd, m, 64);
    }
    if ((lane & (LPH - 1)) == 0) {
        int head = lane / LPH;
        es[node * H + head] = ps;
        ed[node * H + head] = pd;
    }
}

// ---------------- attention aggregation: one wave per dst, bf16 h gather ----------------
template <int F, int H>
__global__ void k_agg(const unsigned short* __restrict__ h,
                      const float* __restrict__ es, const float* __restrict__ ed,
                      const int* __restrict__ cnt, const int* __restrict__ adj,
                      const float* __restrict__ bias,
                      float* __restrict__ out, int n) {
    const int VPL = F / 64;
    const int LPH = 64 / H;
    int lane = threadIdx.x & 63;
    int dst = (blockIdx.x * blockDim.x + threadIdx.x) >> 6;
    if (dst >= n) return;
    int hl = lane / LPH;
    float edc = ed[dst * H + hl];
    int deg = min(cnt[dst], CAP);
    const int* ap = adj + (long)dst * CAP;
    float m = -1e30f;
    for (int i = 0; i < deg; i++) {
        int s = ap[i];
        float e = es[s * H + hl] + edc;
        e = e > 0.f ? e : NEG_SLOPE * e;
        m = fmaxf(m, e);
    }
    float z = 0.f;
    float acc[VPL] = {};
    for (int i = 0; i < deg; i++) {
        int s = ap[i];
        float e = es[s * H + hl] + edc;
        e = e > 0.f ? e : NEG_SLOPE * e;
        float w = __expf(e - m);
        z += w;
        const unsigned short* hp = h + (long)s * F + lane * VPL;
        if (VPL == 4) {
            ushort4 hv = *(const ushort4*)hp;
            acc[0] += w * u2f(hv.x); acc[1] += w * u2f(hv.y);
            acc[2] += w * u2f(hv.z); acc[3] += w * u2f(hv.w);
        } else {
            ushort2 hv = *(const ushort2*)hp;
            acc[0] += w * u2f(hv.x); acc[1] += w * u2f(hv.y);
        }
    }
    float invz = 1.f / z;
    #pragma unroll
    for (int j = 0; j < VPL; j++)
        out[(long)dst * F + lane * VPL + j] = acc[j] * invz + bias[lane * VPL + j];
}

// ---------------- batchnorm ----------------
template <int F>
__global__ void k_bnstats(const float* __restrict__ x, float* bnsum, float* bnsq, int n) {
    int t = threadIdx.x;  // blockDim == F
    float s = 0.f, q = 0.f;
    for (int r = blockIdx.x; r < n; r += gridDim.x) {
        float v = x[(long)r * F + t];
        s += v; q += v * v;
    }
    atomicAdd(&bnsum[t], s);
    atomicAdd(&bnsq[t], q);
}

template <int F>
__global__ void k_bnapply(float* __restrict__ x,
                          const float* __restrict__ bnsum, const float* __restrict__ bnsq,
                          const float* __restrict__ gamma, const float* __restrict__ beta,
                          int n) {
    int idx = blockIdx.x * blockDim.x + threadIdx.x;
    if (idx >= n * F) return;
    int f = idx & (F - 1);
    float invN = 1.f / (float)n;
    float mu = bnsum[f] * invN;
    float var = bnsq[f] * invN - mu * mu;
    float v = (x[idx] - mu) * rsqrtf(var + EPSBN) * gamma[f] + beta[f];
    x[idx] = v > 0.f ? v : 0.f;
}

// ---------------- graph mean-pool: batch is SORTED -> segmented reduction ----------------
static __device__ __forceinline__ int lower_bound_i(const int* __restrict__ a, int n, int v) {
    int lo = 0, hi = n;
    while (lo < hi) { int mid = (lo + hi) >> 1; if (a[mid] < v) lo = mid + 1; else hi = mid; }
    return lo;
}

// grid = G * POOL_SPLIT blocks, 256 threads. One atomicAdd per (block, feature).
__global__ __launch_bounds__(256) void k_pool2(const float* __restrict__ x,
                                               const int* __restrict__ batch,
                                               float* __restrict__ featsum,
                                               int* __restrict__ gcnt, int n) {
    __shared__ float sm[256];
    int g = blockIdx.x / POOL_SPLIT;
    int part = blockIdx.x % POOL_SPLIT;
    int t = threadIdx.x;
    int lo = lower_bound_i(batch, n, g);
    int hi = lower_bound_i(batch, n, g + 1);
    int f = t & 127;
    int phase = t >> 7;  // 0/1: two rows in flight
    float acc = 0.f;
    for (int r = lo + part * 2 + phase; r < hi; r += POOL_SPLIT * 2)
        acc += x[(long)r * 128 + f];
    sm[t] = acc;
    __syncthreads();
    if (t < 128) {
        float s = sm[t] + sm[t + 128];
        atomicAdd(&featsum[g * 128 + t], s);
    }
    if (t == 0 && part == 0) gcnt[g] = hi - lo;
}

// ---------------- heads ----------------
__global__ void k_head(const float* __restrict__ featsum, const int* __restrict__ gcnt,
                       const float* __restrict__ clfW, const float* __restrict__ clfb,
                       const float* __restrict__ dW1, const float* __restrict__ db1,
                       const float* __restrict__ dW2, const float* __restrict__ db2,
                       void* __restrict__ out, const int* flagcnt, int G) {
    __shared__ float feat[128];
    __shared__ float dh[64];
    bool f32o = is_f32(flagcnt);
    float* of = (float*)out;
    __hip_bfloat16* ob = (__hip_bfloat16*)out;
    int g = blockIdx.x, t = threadIdx.x;  // 128 threads
    float c = fmaxf((float)gcnt[g], 1.f);
    float fv = featsum[g * 128 + t] / c;
    feat[t] = fv;
    int fidx = G * 10 + G * 2 + g * 128 + t;
    if (f32o) of[fidx] = fv; else ob[fidx] = __float2bfloat16(fv);
    __syncthreads();
    if (t < 10) {
        float a = clfb[t];
        for (int k = 0; k < 128; k++) a += feat[k] * clfW[k * 10 + t];
        int idx = g * 10 + t;
        if (f32o) of[idx] = a; else ob[idx] = __float2bfloat16(a);
    }
    if (t < 64) {
        float a = db1[t];
        for (int k = 0; k < 128; k++) a += feat[k] * dW1[k * 64 + t];
        dh[t] = a > 0.f ? a : 0.f;
    }
    __syncthreads();
    if (t < 2) {
        float a = db2[t];
        for (int k = 0; k < 64; k++) a += dh[k] * dW2[k * 2 + t];
        int idx = G * 10 + g * 2 + t;
        if (f32o) of[idx] = a; else ob[idx] = __float2bfloat16(a);
    }
}

// ---------------- launch ----------------
extern "C" void kernel_launch(void* const* d_in, const int* in_sizes, int n_in,
                              void* d_out, int out_size, void* d_ws, size_t ws_size,
                              hipStream_t stream) {
    const void* x_in = d_in[0];
    const int* ei    = (const int*)d_in[1];
    const int* batch = (const int*)d_in[2];
    const int N = in_sizes[2];
    const int E = in_sizes[1] / 2;
    const int G = 64;

    // workspace layout (256B aligned chunks)
    char* ws = (char*)d_ws;
    size_t off = 0;
    auto alloc = [&](size_t bytes) {
        void* p = ws + off;
        off += (bytes + 255) & ~(size_t)255;
        return p;
    };
    int*   flagcnt = (int*)alloc(256);
    int*   cnt     = (int*)alloc((size_t)N * 4);
    int*   adj     = (int*)alloc((size_t)N * CAP * 4);
    float* xbuf    = (float*)alloc((size_t)N * 256 * 4);
    unsigned short* hbuf = (unsigned short*)alloc((size_t)N * 256 * 2);  // bf16 h
    float* es      = (float*)alloc((size_t)N * 4 * 4);
    float* ed      = (float*)alloc((size_t)N * 4 * 4);
    float* bnsum   = (float*)alloc(256 * 4 + 256 * 4);
    float* bnsq    = bnsum + 256;
    float* featsum = (float*)alloc((size_t)G * 128 * 4 + (size_t)G * 4);
    int*   gcnt    = (int*)(featsum + G * 128);

    // fp32 copies of the 24 float param tensors (d_in[3..26])
    CvtTab tab;
    float* pp[NPARAM];
    int ptot = 0;
    for (int j = 0; j < NPARAM; j++) {
        int cnt_j = in_sizes[3 + j];
        pp[j] = (float*)alloc((size_t)cnt_j * 4);
        tab.src[j] = d_in[3 + j];
        tab.dst[j] = pp[j];
        tab.off[j] = ptot;
        ptot += cnt_j;
    }
    tab.off[NPARAM] = ptot;
    float *Wf0 = pp[0], *asf0 = pp[1], *adf0 = pp[2], *bf0 = pp[3], *gf0 = pp[4], *bef0 = pp[5];
    float *Wf1 = pp[6], *asf1 = pp[7], *adf1 = pp[8], *bf1 = pp[9], *gf1 = pp[10], *bef1 = pp[11];
    float *Wf2 = pp[12], *asf2 = pp[13], *adf2 = pp[14], *bf2 = pp[15], *gf2 = pp[16], *bef2 = pp[17];
    float *clfWf = pp[18], *clfbf = pp[19], *dW1f = pp[20], *db1f = pp[21], *dW2f = pp[22], *db2f = pp[23];

    const int TPB = 256;
    int wgrid = (N + 3) / 4;  // one wave per node

    // dtype probe + converts
    hipMemsetAsync(flagcnt, 0, 4, stream);
    k_detect<<<1, 256, 0, stream>>>((const unsigned short*)x_in, flagcnt);
    k_cvt_x<<<(N * 128 + TPB - 1) / TPB, TPB, 0, stream>>>(x_in, xbuf, flagcnt, N * 128);
    k_cvt_params<<<(ptot + TPB - 1) / TPB, TPB, 0, stream>>>(tab, flagcnt, ptot);

    // graph build
    k_init_graph<<<(N + TPB - 1) / TPB, TPB, 0, stream>>>(cnt, adj, N);
    k_fill_graph<<<(E + TPB - 1) / TPB, TPB, 0, stream>>>(ei, cnt, adj, E);

    // ---- layer 0: K=128 -> F=256, H=4, D=64 ----
    {
        dim3 grid((N + 63) / 64, 256 / 64);
        k_gemm<<<grid, 256, 0, stream>>>(xbuf, Wf0, hbuf, N, 128, 256, 128);
        k_attn<256, 4><<<wgrid, 256, 0, stream>>>(hbuf, asf0, adf0, es, ed, N);
        k_agg<256, 4><<<wgrid, 256, 0, stream>>>(hbuf, es, ed, cnt, adj, bf0, xbuf, N);
        hipMemsetAsync(bnsum, 0, 2048, stream);
        k_bnstats<256><<<160, 256, 0, stream>>>(xbuf, bnsum, bnsq, N);
        k_bnapply<256><<<(N * 256 + TPB - 1) / TPB, TPB, 0, stream>>>(xbuf, bnsum, bnsq, gf0, bef0, N);
    }
    // ---- layer 1: K=256 -> F=256, H=4, D=64 ----
    {
        dim3 grid((N + 63) / 64, 256 / 64);
        k_gemm<<<grid, 256, 0, stream>>>(xbuf, Wf1, hbuf, N, 256, 256, 256);
        k_attn<256, 4><<<wgrid, 256, 0, stream>>>(hbuf, asf1, adf1, es, ed, N);
        k_agg<256, 4><<<wgrid, 256, 0, stream>>>(hbuf, es, ed, cnt, adj, bf1, xbuf, N);
        hipMemsetAsync(bnsum, 0, 2048, stream);
        k_bnstats<256><<<160, 256, 0, stream>>>(xbuf, bnsum, bnsq, N);
        k_bnapply<256><<<(N * 256 + TPB - 1) / TPB, TPB, 0, stream>>>(xbuf, bnsum, bnsq, gf1, bef1, N);
    }
    // ---- layer 2: K=256 -> F=128, H=1, D=128 ----
    {
        dim3 grid((N + 63) / 64, 128 / 64);
        k_gemm<<<grid, 256, 0, stream>>>(xbuf, Wf2, hbuf, N, 256, 128, 256);
        k_attn<128, 1><<<wgrid, 256, 0, stream>>>(hbuf, asf2, adf2, es, ed, N);
        k_agg<128, 1><<<wgrid, 256, 0, stream>>>(hbuf, es, ed, cnt, adj, bf2, xbuf, N);
        hipMemsetAsync(bnsum, 0, 2048, stream);
        k_bnstats<128><<<160, 128, 0, stream>>>(xbuf, bnsum, bnsq, N);
        k_bnapply<128><<<(N * 128 + TPB - 1) / TPB, TPB, 0, stream>>>(xbuf, bnsum, bnsq, gf2, bef2, N);
    }

    // ---- pooling + heads ----
    hipMemsetAsync(featsum, 0, (size_t)G * 128 * 4 + (size_t)G * 4, stream);
    k_pool2<<<G * POOL_SPLIT, 256, 0, stream>>>(xbuf, batch, featsum, gcnt, N);
    k_head<<<G, 128, 0, stream>>>(featsum, gcnt, clfWf, clfbf, dW1f, db1f, dW2f, db2f,
                                  d_out, flagcnt, G);
}

// Round 5
// 512.569 us; speedup vs baseline: 1.4372x; 1.1764x over previous
//
#include <hip/hip_runtime.h>
#include <hip/hip_bf16.h>

#define CAP 64          // max in-degree capacity per dst (incl self-loop); Poisson(~17) tail negligible
#define EPSBN 1e-5f
#define NEG_SLOPE 0.2f
#define NPARAM 24       // float param tensors: d_in[3..26]
#define POOL_SPLIT 4    // blocks per graph in pooling

static __device__ __forceinline__ float b2f(__hip_bfloat16 v) { return __bfloat162float(v); }
static __device__ __forceinline__ float u2f(unsigned short u) {  // bf16 bits -> float
    return __uint_as_float(((unsigned int)u) << 16);
}
static __device__ __forceinline__ unsigned short f2b_rne(float f) {  // float -> bf16 bits, RNE
    unsigned int u = __float_as_uint(f);
    u += 0x7FFF + ((u >> 16) & 1);
    return (unsigned short)(u >> 16);
}
static __device__ __forceinline__ float rdlane(float v, int i) {
    return __uint_as_float(__builtin_amdgcn_readlane(__float_as_uint(v), i));
}
static __device__ __forceinline__ bool is_f32(const int* flagcnt) { return *flagcnt > 32; }

// ---------------- dtype probe: count huge-exponent bf16 interpretations ----------------
__global__ void k_detect(const unsigned short* __restrict__ raw, int* flagcnt) {
    int t = threadIdx.x;  // 256 threads, 1 block
    int c = 0;
    for (int i = t; i < 4096; i += 256) {
        int e = (raw[i] >> 7) & 0xFF;
        if (e >= 200) c++;  // |v| >= ~2^73 — never happens for N(0,1) bf16 data
    }
    atomicAdd(flagcnt, c);
}

// ---------------- dtype-aware converts ----------------
__global__ void k_cvt_x(const void* __restrict__ src, float* __restrict__ dst,
                        const int* flagcnt, int total) {
    bool f32 = is_f32(flagcnt);
    int i = blockIdx.x * blockDim.x + threadIdx.x;
    if (i < total)
        dst[i] = f32 ? ((const float*)src)[i] : b2f(((const __hip_bfloat16*)src)[i]);
}

struct CvtTab {
    const void* src[NPARAM];
    float* dst[NPARAM];
    int off[NPARAM + 1];
};

__global__ void k_cvt_params(CvtTab tab, const int* flagcnt, int total) {
    bool f32 = is_f32(flagcnt);
    for (int i = blockIdx.x * blockDim.x + threadIdx.x; i < total; i += gridDim.x * blockDim.x) {
        int j = 0;
        while (tab.off[j + 1] <= i) j++;
        int k = i - tab.off[j];
        tab.dst[j][k] = f32 ? ((const float*)tab.src[j])[k]
                            : b2f(((const __hip_bfloat16*)tab.src[j])[k]);
    }
}

// ---------------- graph build ----------------
__global__ void k_init_graph(int* cnt, int* adj, int n) {
    int i = blockIdx.x * blockDim.x + threadIdx.x;
    if (i < n) { cnt[i] = 1; adj[i * CAP] = i; }  // self-loop in slot 0
}

__global__ void k_fill_graph(const int* __restrict__ ei, int* cnt, int* adj, int E) {
    int e = blockIdx.x * blockDim.x + threadIdx.x;
    if (e < E) {
        int s = ei[e];
        int d = ei[E + e];
        int slot = atomicAdd(&cnt[d], 1);
        if (slot < CAP) adj[d * CAP + slot] = s;
    }
}

// ---------------- fp32 GEMM -> bf16 C: C[M,F] = A[M,K](lda) @ B[K,F] ----------------
__global__ __launch_bounds__(256) void k_gemm(const float* __restrict__ A,
                                              const float* __restrict__ B,
                                              unsigned short* __restrict__ C,
                                              int M, int K, int F, int lda) {
    __shared__ float As[16][65];
    __shared__ float Bs[16][64];
    int t = threadIdx.x;
    int tx = t & 15, ty = t >> 4;
    int rowBase = blockIdx.x * 64;
    int colBase = blockIdx.y * 64;
    float acc[4][4] = {};
    for (int k0 = 0; k0 < K; k0 += 16) {
        #pragma unroll
        for (int i = 0; i < 4; i++) {
            int idx = t + 256 * i;
            int r = idx >> 4, c = idx & 15;
            int gr = rowBase + r;
            As[c][r] = (gr < M) ? A[(long)gr * lda + k0 + c] : 0.f;
        }
        #pragma unroll
        for (int i = 0; i < 4; i++) {
            int idx = t + 256 * i;
            int r = idx >> 6, c = idx & 63;
            Bs[r][c] = B[(long)(k0 + r) * F + colBase + c];
        }
        __syncthreads();
        #pragma unroll
        for (int kk = 0; kk < 16; kk++) {
            float a[4], b[4];
            #pragma unroll
            for (int i = 0; i < 4; i++) a[i] = As[kk][ty * 4 + i];
            #pragma unroll
            for (int j = 0; j < 4; j++) b[j] = Bs[kk][tx * 4 + j];
            #pragma unroll
            for (int i = 0; i < 4; i++)
                #pragma unroll
                for (int j = 0; j < 4; j++) acc[i][j] += a[i] * b[j];
        }
        __syncthreads();
    }
    #pragma unroll
    for (int i = 0; i < 4; i++) {
        int gr = rowBase + ty * 4 + i;
        if (gr < M) {
            ushort4 pk;
            pk.x = f2b_rne(acc[i][0]); pk.y = f2b_rne(acc[i][1]);
            pk.z = f2b_rne(acc[i][2]); pk.w = f2b_rne(acc[i][3]);
            *(ushort4*)(C + (long)gr * F + colBase + tx * 4) = pk;
        }
    }
}

// ---------------- attention coefficients: es/ed [N,H], one wave per node ----------------
template <int F, int H>
__global__ void k_attn(const unsigned short* __restrict__ h,
                       const float* __restrict__ a_s,
                       const float* __restrict__ a_d,
                       float* __restrict__ es, float* __restrict__ ed, int n) {
    const int VPL = F / 64;
    const int LPH = 64 / H;
    int lane = threadIdx.x & 63;
    int node = (blockIdx.x * blockDim.x + threadIdx.x) >> 6;
    if (node >= n) return;
    float hv[VPL];
    const unsigned short* hp = h + (long)node * F + lane * VPL;
    if (VPL == 4) {
        ushort4 p = *(const ushort4*)hp;
        hv[0] = u2f(p.x); hv[1] = u2f(p.y); hv[2] = u2f(p.z); hv[3] = u2f(p.w);
    } else {
        ushort2 p = *(const ushort2*)hp;
        hv[0] = u2f(p.x); hv[1] = u2f(p.y);
    }
    float ps = 0.f, pd = 0.f;
    #pragma unroll
    for (int j = 0; j < VPL; j++) {
        ps += hv[j] * a_s[lane * VPL + j];
        pd += hv[j] * a_d[lane * VPL + j];
    }
    #pragma unroll
    for (int m = 1; m < LPH; m <<= 1) {
        ps += __shfl_xor(ps, m, 64);
        pd += __shfl_xor(pd, m, 64);
    }
    if ((lane & (LPH - 1)) == 0) {
        int head = lane / LPH;
        es[node * H + head] = ps;
        ed[node * H + head] = pd;
    }
}

// ---------------- attention aggregation: one wave per dst, single pass ----------------
// No max subtraction: e = leaky(es+ed) is bounded by data scale (|e| < ~10), exp() is
// safe in fp32, and softmax w/z is shift-invariant -> same result as reference.
// Lane l preloads neighbor l's index + es (deg <= CAP = 64 = wave size); the loop
// broadcasts via readlane (wave-uniform loop index), leaving ONE memory op per
// iteration: the coalesced bf16 h-row gather.
template <int F, int H>
__global__ __launch_bounds__(256) void k_agg(const unsigned short* __restrict__ h,
                      const float* __restrict__ es, const float* __restrict__ ed,
                      const int* __restrict__ cnt, const int* __restrict__ adj,
                      const float* __restrict__ bias,
                      float* __restrict__ out, int n) {
    const int VPL = F / 64;
    const int LPH = 64 / H;
    int lane = threadIdx.x & 63;
    int dst = (blockIdx.x * blockDim.x + threadIdx.x) >> 6;
    if (dst >= n) return;
    int hl = lane / LPH;
    float edc = ed[dst * H + hl];
    int deg = min(cnt[dst], CAP);
    const int* ap = adj + (long)dst * CAP;
    // per-lane preload of neighbor index + es (all heads)
    int sl = ap[lane < deg ? lane : 0];
    float e0, e1, e2, e3;
    if (H == 4) {
        float4 v = *(const float4*)(es + (long)sl * 4);
        e0 = v.x; e1 = v.y; e2 = v.z; e3 = v.w;
    } else {
        e0 = es[sl];
        e1 = e2 = e3 = 0.f;
    }
    bool selA = (hl & 1) != 0, selB = (hl & 2) != 0;
    float z = 0.f;
    float acc[VPL] = {};
    #pragma unroll 2
    for (int i = 0; i < deg; i++) {
        int s = __builtin_amdgcn_readlane(sl, i);
        float e_s;
        if (H == 4) {
            float b0 = rdlane(e0, i), b1 = rdlane(e1, i);
            float b2v = rdlane(e2, i), b3 = rdlane(e3, i);
            float lo = selA ? b1 : b0;
            float hi = selA ? b3 : b2v;
            e_s = selB ? hi : lo;
        } else {
            e_s = rdlane(e0, i);
        }
        float e = e_s + edc;
        e = fmaxf(e, NEG_SLOPE * e);   // leaky_relu
        float w = __expf(e);
        z += w;
        const unsigned short* hp = h + (long)s * F + lane * VPL;
        if (VPL == 4) {
            uint2 hv = *(const uint2*)hp;
            acc[0] += w * __uint_as_float(hv.x << 16);
            acc[1] += w * __uint_as_float(hv.x & 0xffff0000u);
            acc[2] += w * __uint_as_float(hv.y << 16);
            acc[3] += w * __uint_as_float(hv.y & 0xffff0000u);
        } else {
            unsigned int hv = *(const unsigned int*)hp;
            acc[0] += w * __uint_as_float(hv << 16);
            acc[1] += w * __uint_as_float(hv & 0xffff0000u);
        }
    }
    float invz = 1.f / z;
    #pragma unroll
    for (int j = 0; j < VPL; j++)
        out[(long)dst * F + lane * VPL + j] = acc[j] * invz + bias[lane * VPL + j];
}

// ---------------- batchnorm ----------------
template <int F>
__global__ void k_bnstats(const float* __restrict__ x, float* bnsum, float* bnsq, int n) {
    int t = threadIdx.x;  // blockDim == F
    float s = 0.f, q = 0.f;
    for (int r = blockIdx.x; r < n; r += gridDim.x) {
        float v = x[(long)r * F + t];
        s += v; q += v * v;
    }
    atomicAdd(&bnsum[t], s);
    atomicAdd(&bnsq[t], q);
}

template <int F>
__global__ void k_bnapply(float* __restrict__ x,
                          const float* __restrict__ bnsum, const float* __restrict__ bnsq,
                          const float* __restrict__ gamma, const float* __restrict__ beta,
                          int n) {
    int idx = blockIdx.x * blockDim.x + threadIdx.x;
    if (idx >= n * F) return;
    int f = idx & (F - 1);
    float invN = 1.f / (float)n;
    float mu = bnsum[f] * invN;
    float var = bnsq[f] * invN - mu * mu;
    float v = (x[idx] - mu) * rsqrtf(var + EPSBN) * gamma[f] + beta[f];
    x[idx] = v > 0.f ? v : 0.f;
}

// ---------------- graph mean-pool: batch is SORTED -> segmented reduction ----------------
static __device__ __forceinline__ int lower_bound_i(const int* __restrict__ a, int n, int v) {
    int lo = 0, hi = n;
    while (lo < hi) { int mid = (lo + hi) >> 1; if (a[mid] < v) lo = mid + 1; else hi = mid; }
    return lo;
}

// grid = G * POOL_SPLIT blocks, 256 threads. One atomicAdd per (block, feature).
__global__ __launch_bounds__(256) void k_pool2(const float* __restrict__ x,
                                               const int* __restrict__ batch,
                                               float* __restrict__ featsum,
                                               int* __restrict__ gcnt, int n) {
    __shared__ float sm[256];
    int g = blockIdx.x / POOL_SPLIT;
    int part = blockIdx.x % POOL_SPLIT;
    int t = threadIdx.x;
    int lo = lower_bound_i(batch, n, g);
    int hi = lower_bound_i(batch, n, g + 1);
    int f = t & 127;
    int phase = t >> 7;  // 0/1: two rows in flight
    float acc = 0.f;
    for (int r = lo + part * 2 + phase; r < hi; r += POOL_SPLIT * 2)
        acc += x[(long)r * 128 + f];
    sm[t] = acc;
    __syncthreads();
    if (t < 128) {
        float s = sm[t] + sm[t + 128];
        atomicAdd(&featsum[g * 128 + t], s);
    }
    if (t == 0 && part == 0) gcnt[g] = hi - lo;
}

// ---------------- heads ----------------
__global__ void k_head(const float* __restrict__ featsum, const int* __restrict__ gcnt,
                       const float* __restrict__ clfW, const float* __restrict__ clfb,
                       const float* __restrict__ dW1, const float* __restrict__ db1,
                       const float* __restrict__ dW2, const float* __restrict__ db2,
                       void* __restrict__ out, const int* flagcnt, int G) {
    __shared__ float feat[128];
    __shared__ float dh[64];
    bool f32o = is_f32(flagcnt);
    float* of = (float*)out;
    __hip_bfloat16* ob = (__hip_bfloat16*)out;
    int g = blockIdx.x, t = threadIdx.x;  // 128 threads
    float c = fmaxf((float)gcnt[g], 1.f);
    float fv = featsum[g * 128 + t] / c;
    feat[t] = fv;
    int fidx = G * 10 + G * 2 + g * 128 + t;
    if (f32o) of[fidx] = fv; else ob[fidx] = __float2bfloat16(fv);
    __syncthreads();
    if (t < 10) {
        float a = clfb[t];
        for (int k = 0; k < 128; k++) a += feat[k] * clfW[k * 10 + t];
        int idx = g * 10 + t;
        if (f32o) of[idx] = a; else ob[idx] = __float2bfloat16(a);
    }
    if (t < 64) {
        float a = db1[t];
        for (int k = 0; k < 128; k++) a += feat[k] * dW1[k * 64 + t];
        dh[t] = a > 0.f ? a : 0.f;
    }
    __syncthreads();
    if (t < 2) {
        float a = db2[t];
        for (int k = 0; k < 64; k++) a += dh[k] * dW2[k * 2 + t];
        int idx = G * 10 + g * 2 + t;
        if (f32o) of[idx] = a; else ob[idx] = __float2bfloat16(a);
    }
}

// ---------------- launch ----------------
extern "C" void kernel_launch(void* const* d_in, const int* in_sizes, int n_in,
                              void* d_out, int out_size, void* d_ws, size_t ws_size,
                              hipStream_t stream) {
    const void* x_in = d_in[0];
    const int* ei    = (const int*)d_in[1];
    const int* batch = (const int*)d_in[2];
    const int N = in_sizes[2];
    const int E = in_sizes[1] / 2;
    const int G = 64;

    // workspace layout (256B aligned chunks)
    char* ws = (char*)d_ws;
    size_t off = 0;
    auto alloc = [&](size_t bytes) {
        void* p = ws + off;
        off += (bytes + 255) & ~(size_t)255;
        return p;
    };
    int*   flagcnt = (int*)alloc(256);
    int*   cnt     = (int*)alloc((size_t)N * 4);
    int*   adj     = (int*)alloc((size_t)N * CAP * 4);
    float* xbuf    = (float*)alloc((size_t)N * 256 * 4);
    unsigned short* hbuf = (unsigned short*)alloc((size_t)N * 256 * 2);  // bf16 h
    float* es      = (float*)alloc((size_t)N * 4 * 4);
    float* ed      = (float*)alloc((size_t)N * 4 * 4);
    float* bnsum   = (float*)alloc(256 * 4 + 256 * 4);
    float* bnsq    = bnsum + 256;
    float* featsum = (float*)alloc((size_t)G * 128 * 4 + (size_t)G * 4);
    int*   gcnt    = (int*)(featsum + G * 128);

    // fp32 copies of the 24 float param tensors (d_in[3..26])
    CvtTab tab;
    float* pp[NPARAM];
    int ptot = 0;
    for (int j = 0; j < NPARAM; j++) {
        int cnt_j = in_sizes[3 + j];
        pp[j] = (float*)alloc((size_t)cnt_j * 4);
        tab.src[j] = d_in[3 + j];
        tab.dst[j] = pp[j];
        tab.off[j] = ptot;
        ptot += cnt_j;
    }
    tab.off[NPARAM] = ptot;
    float *Wf0 = pp[0], *asf0 = pp[1], *adf0 = pp[2], *bf0 = pp[3], *gf0 = pp[4], *bef0 = pp[5];
    float *Wf1 = pp[6], *asf1 = pp[7], *adf1 = pp[8], *bf1 = pp[9], *gf1 = pp[10], *bef1 = pp[11];
    float *Wf2 = pp[12], *asf2 = pp[13], *adf2 = pp[14], *bf2 = pp[15], *gf2 = pp[16], *bef2 = pp[17];
    float *clfWf = pp[18], *clfbf = pp[19], *dW1f = pp[20], *db1f = pp[21], *dW2f = pp[22], *db2f = pp[23];

    const int TPB = 256;
    int wgrid = (N + 3) / 4;  // one wave per node

    // dtype probe + converts
    hipMemsetAsync(flagcnt, 0, 4, stream);
    k_detect<<<1, 256, 0, stream>>>((const unsigned short*)x_in, flagcnt);
    k_cvt_x<<<(N * 128 + TPB - 1) / TPB, TPB, 0, stream>>>(x_in, xbuf, flagcnt, N * 128);
    k_cvt_params<<<(ptot + TPB - 1) / TPB, TPB, 0, stream>>>(tab, flagcnt, ptot);

    // graph build
    k_init_graph<<<(N + TPB - 1) / TPB, TPB, 0, stream>>>(cnt, adj, N);
    k_fill_graph<<<(E + TPB - 1) / TPB, TPB, 0, stream>>>(ei, cnt, adj, E);

    // ---- layer 0: K=128 -> F=256, H=4, D=64 ----
    {
        dim3 grid((N + 63) / 64, 256 / 64);
        k_gemm<<<grid, 256, 0, stream>>>(xbuf, Wf0, hbuf, N, 128, 256, 128);
        k_attn<256, 4><<<wgrid, 256, 0, stream>>>(hbuf, asf0, adf0, es, ed, N);
        k_agg<256, 4><<<wgrid, 256, 0, stream>>>(hbuf, es, ed, cnt, adj, bf0, xbuf, N);
        hipMemsetAsync(bnsum, 0, 2048, stream);
        k_bnstats<256><<<160, 256, 0, stream>>>(xbuf, bnsum, bnsq, N);
        k_bnapply<256><<<(N * 256 + TPB - 1) / TPB, TPB, 0, stream>>>(xbuf, bnsum, bnsq, gf0, bef0, N);
    }
    // ---- layer 1: K=256 -> F=256, H=4, D=64 ----
    {
        dim3 grid((N + 63) / 64, 256 / 64);
        k_gemm<<<grid, 256, 0, stream>>>(xbuf, Wf1, hbuf, N, 256, 256, 256);
        k_attn<256, 4><<<wgrid, 256, 0, stream>>>(hbuf, asf1, adf1, es, ed, N);
        k_agg<256, 4><<<wgrid, 256, 0, stream>>>(hbuf, es, ed, cnt, adj, bf1, xbuf, N);
        hipMemsetAsync(bnsum, 0, 2048, stream);
        k_bnstats<256><<<160, 256, 0, stream>>>(xbuf, bnsum, bnsq, N);
        k_bnapply<256><<<(N * 256 + TPB - 1) / TPB, TPB, 0, stream>>>(xbuf, bnsum, bnsq, gf1, bef1, N);
    }
    // ---- layer 2: K=256 -> F=128, H=1, D=128 ----
    {
        dim3 grid((N + 63) / 64, 128 / 64);
        k_gemm<<<grid, 256, 0, stream>>>(xbuf, Wf2, hbuf, N, 256, 128, 256);
        k_attn<128, 1><<<wgrid, 256, 0, stream>>>(hbuf, asf2, adf2, es, ed, N);
        k_agg<128, 1><<<wgrid, 256, 0, stream>>>(hbuf, es, ed, cnt, adj, bf2, xbuf, N);
        hipMemsetAsync(bnsum, 0, 2048, stream);
        k_bnstats<128><<<160, 128, 0, stream>>>(xbuf, bnsum, bnsq, N);
        k_bnapply<128><<<(N * 128 + TPB - 1) / TPB, TPB, 0, stream>>>(xbuf, bnsum, bnsq, gf2, bef2, N);
    }

    // ---- pooling + heads ----
    hipMemsetAsync(featsum, 0, (size_t)G * 128 * 4 + (size_t)G * 4, stream);
    k_pool2<<<G * POOL_SPLIT, 256, 0, stream>>>(xbuf, batch, featsum, gcnt, N);
    k_head<<<G, 128, 0, stream>>>(featsum, gcnt, clfWf, clfbf, dW1f, db1f, dW2f, db2f,
                                  d_out, flagcnt, G);
}

// Round 6
// 435.743 us; speedup vs baseline: 1.6906x; 1.1763x over previous
//
#include <hip/hip_runtime.h>
#include <hip/hip_bf16.h>

#define CAP 64          // max in-degree capacity per dst (incl self-loop); Poisson(~17) tail negligible
#define EPSBN 1e-5f
#define NEG_SLOPE 0.2f
#define NPARAM 24       // float param tensors: d_in[3..26]
#define POOL_SPLIT 4    // blocks per graph in pooling

typedef __attribute__((ext_vector_type(8))) short short8;
typedef __attribute__((ext_vector_type(4))) float f32x4;

static __device__ __forceinline__ float b2f(__hip_bfloat16 v) { return __bfloat162float(v); }
static __device__ __forceinline__ float u2f(unsigned short u) {  // bf16 bits -> float
    return __uint_as_float(((unsigned int)u) << 16);
}
static __device__ __forceinline__ unsigned short f2b_rne(float f) {  // float -> bf16 bits, RNE
    unsigned int u = __float_as_uint(f);
    u += 0x7FFF + ((u >> 16) & 1);
    return (unsigned short)(u >> 16);
}
static __device__ __forceinline__ float rdlane(float v, int i) {
    return __uint_as_float(__builtin_amdgcn_readlane(__float_as_uint(v), i));
}
static __device__ __forceinline__ bool is_f32(const int* flagcnt) { return *flagcnt > 32; }

// ---------------- dtype probe: count huge-exponent bf16 interpretations ----------------
__global__ void k_detect(const unsigned short* __restrict__ raw, int* flagcnt) {
    int t = threadIdx.x;  // 256 threads, 1 block
    int c = 0;
    for (int i = t; i < 4096; i += 256) {
        int e = (raw[i] >> 7) & 0xFF;
        if (e >= 200) c++;  // |v| >= ~2^73 — never happens for N(0,1) bf16 data
    }
    atomicAdd(flagcnt, c);
}

// ---------------- dtype-aware converts ----------------
// x -> bf16 (MFMA A operand for layer 0)
__global__ void k_cvt_xb(const void* __restrict__ src, unsigned short* __restrict__ dst,
                         const int* flagcnt, int total) {
    bool f32 = is_f32(flagcnt);
    int i = blockIdx.x * blockDim.x + threadIdx.x;
    if (i < total)
        dst[i] = f32 ? f2b_rne(((const float*)src)[i]) : ((const unsigned short*)src)[i];
}

struct CvtTab {
    const void* src[NPARAM];
    float* dst[NPARAM];
    int off[NPARAM + 1];
};

__global__ void k_cvt_params(CvtTab tab, const int* flagcnt, int total) {
    bool f32 = is_f32(flagcnt);
    for (int i = blockIdx.x * blockDim.x + threadIdx.x; i < total; i += gridDim.x * blockDim.x) {
        int j = 0;
        while (tab.off[j + 1] <= i) j++;
        int k = i - tab.off[j];
        tab.dst[j][k] = f32 ? ((const float*)tab.src[j])[k]
                            : b2f(((const __hip_bfloat16*)tab.src[j])[k]);
    }
}

// W [K,F] fp32 -> Wt [F,K] bf16 (coalesced write; tiny matrix)
__global__ void k_transW(const float* __restrict__ W, unsigned short* __restrict__ Wt,
                         int K, int F) {
    int i = blockIdx.x * blockDim.x + threadIdx.x;
    if (i < K * F) {
        int f = i / K, k = i - f * K;
        Wt[i] = f2b_rne(W[(long)k * F + f]);
    }
}

// ---------------- graph build ----------------
__global__ void k_init_graph(int* cnt, int* adj, int n) {
    int i = blockIdx.x * blockDim.x + threadIdx.x;
    if (i < n) { cnt[i] = 1; adj[i * CAP] = i; }  // self-loop in slot 0
}

__global__ void k_fill_graph(const int* __restrict__ ei, int* cnt, int* adj, int E) {
    int e = blockIdx.x * blockDim.x + threadIdx.x;
    if (e < E) {
        int s = ei[e];
        int d = ei[E + e];
        int slot = atomicAdd(&cnt[d], 1);
        if (slot < CAP) adj[d * CAP + slot] = s;
    }
}

// ---------------- bf16 MFMA GEMM: C[M,F] = A[M,K] @ Bt[F,K]^T, all bf16, fp32 accum ----
// 64x64 tile, BK=32, 256 thr = 4 waves in 2x2; each wave 32x32 via 2x2 16x16x32 MFMAs.
// LDS rows padded to 40 elems (80B) -> <=2-way bank aliasing (free).
// A-frag: A[m=lane&15][k=quad*8+j]; B-frag from B^T rows; C/D: col=lane&15, row=quad*4+reg.
__global__ __launch_bounds__(256) void k_gemm_mfma(const unsigned short* __restrict__ A,
                                                   const unsigned short* __restrict__ Bt,
                                                   unsigned short* __restrict__ C,
                                                   int M, int K, int F) {
    __shared__ __align__(16) unsigned short As[64 * 40];
    __shared__ __align__(16) unsigned short Bs[64 * 40];
    int t = threadIdx.x;
    int lane = t & 63, wave = t >> 6;
    int wm = wave & 1, wf = wave >> 1;
    int m0 = blockIdx.x * 64, f0 = blockIdx.y * 64;
    int r = lane & 15, q = lane >> 4;
    int srow = t >> 2, schunk = t & 3;
    f32x4 acc[2][2] = {};
    for (int k0 = 0; k0 < K; k0 += 32) {
        uint4 av = {0, 0, 0, 0};
        int gr = m0 + srow;
        if (gr < M) av = *(const uint4*)(A + (long)gr * K + k0 + schunk * 8);
        *(uint4*)&As[srow * 40 + schunk * 8] = av;
        uint4 bv = *(const uint4*)(Bt + (long)(f0 + srow) * K + k0 + schunk * 8);
        *(uint4*)&Bs[srow * 40 + schunk * 8] = bv;
        __syncthreads();
        short8 a0 = *(short8*)&As[(wm * 32 + r) * 40 + q * 8];
        short8 a1 = *(short8*)&As[(wm * 32 + 16 + r) * 40 + q * 8];
        short8 b0 = *(short8*)&Bs[(wf * 32 + r) * 40 + q * 8];
        short8 b1 = *(short8*)&Bs[(wf * 32 + 16 + r) * 40 + q * 8];
        acc[0][0] = __builtin_amdgcn_mfma_f32_16x16x32_bf16(a0, b0, acc[0][0], 0, 0, 0);
        acc[0][1] = __builtin_amdgcn_mfma_f32_16x16x32_bf16(a0, b1, acc[0][1], 0, 0, 0);
        acc[1][0] = __builtin_amdgcn_mfma_f32_16x16x32_bf16(a1, b0, acc[1][0], 0, 0, 0);
        acc[1][1] = __builtin_amdgcn_mfma_f32_16x16x32_bf16(a1, b1, acc[1][1], 0, 0, 0);
        __syncthreads();
    }
    #pragma unroll
    for (int mt = 0; mt < 2; mt++) {
        int rowb = m0 + wm * 32 + mt * 16 + q * 4;
        #pragma unroll
        for (int reg = 0; reg < 4; reg++) {
            int row = rowb + reg;
            if (row < M) {
                #pragma unroll
                for (int ft = 0; ft < 2; ft++) {
                    int col = f0 + wf * 32 + ft * 16 + r;
                    C[(long)row * F + col] = f2b_rne(acc[mt][ft][reg]);
                }
            }
        }
    }
}

// ---------------- attention coefficients: es/ed [N,H], one wave per node ----------------
template <int F, int H>
__global__ void k_attn(const unsigned short* __restrict__ h,
                       const float* __restrict__ a_s,
                       const float* __restrict__ a_d,
                       float* __restrict__ es, float* __restrict__ ed, int n) {
    const int VPL = F / 64;
    const int LPH = 64 / H;
    int lane = threadIdx.x & 63;
    int node = (blockIdx.x * blockDim.x + threadIdx.x) >> 6;
    if (node >= n) return;
    float hv[VPL];
    const unsigned short* hp = h + (long)node * F + lane * VPL;
    if (VPL == 4) {
        ushort4 p = *(const ushort4*)hp;
        hv[0] = u2f(p.x); hv[1] = u2f(p.y); hv[2] = u2f(p.z); hv[3] = u2f(p.w);
    } else {
        ushort2 p = *(const ushort2*)hp;
        hv[0] = u2f(p.x); hv[1] = u2f(p.y);
    }
    float ps = 0.f, pd = 0.f;
    #pragma unroll
    for (int j = 0; j < VPL; j++) {
        ps += hv[j] * a_s[lane * VPL + j];
        pd += hv[j] * a_d[lane * VPL + j];
    }
    #pragma unroll
    for (int m = 1; m < LPH; m <<= 1) {
        ps += __shfl_xor(ps, m, 64);
        pd += __shfl_xor(pd, m, 64);
    }
    if ((lane & (LPH - 1)) == 0) {
        int head = lane / LPH;
        es[node * H + head] = ps;
        ed[node * H + head] = pd;
    }
}

// ---------------- attention aggregation: one wave per dst, single pass ----------------
template <int F, int H>
__global__ __launch_bounds__(256) void k_agg(const unsigned short* __restrict__ h,
                      const float* __restrict__ es, const float* __restrict__ ed,
                      const int* __restrict__ cnt, const int* __restrict__ adj,
                      const float* __restrict__ bias,
                      float* __restrict__ out, int n) {
    const int VPL = F / 64;
    const int LPH = 64 / H;
    int lane = threadIdx.x & 63;
    int dst = (blockIdx.x * blockDim.x + threadIdx.x) >> 6;
    if (dst >= n) return;
    int hl = lane / LPH;
    float edc = ed[dst * H + hl];
    int deg = min(cnt[dst], CAP);
    const int* ap = adj + (long)dst * CAP;
    int sl = ap[lane < deg ? lane : 0];
    float e0, e1, e2, e3;
    if (H == 4) {
        float4 v = *(const float4*)(es + (long)sl * 4);
        e0 = v.x; e1 = v.y; e2 = v.z; e3 = v.w;
    } else {
        e0 = es[sl];
        e1 = e2 = e3 = 0.f;
    }
    bool selA = (hl & 1) != 0, selB = (hl & 2) != 0;
    float z = 0.f;
    float acc[VPL] = {};
    #pragma unroll 2
    for (int i = 0; i < deg; i++) {
        int s = __builtin_amdgcn_readlane(sl, i);
        float e_s;
        if (H == 4) {
            float b0 = rdlane(e0, i), b1 = rdlane(e1, i);
            float b2v = rdlane(e2, i), b3 = rdlane(e3, i);
            float lo = selA ? b1 : b0;
            float hi = selA ? b3 : b2v;
            e_s = selB ? hi : lo;
        } else {
            e_s = rdlane(e0, i);
        }
        float e = e_s + edc;
        e = fmaxf(e, NEG_SLOPE * e);   // leaky_relu
        float w = __expf(e);
        z += w;
        const unsigned short* hp = h + (long)s * F + lane * VPL;
        if (VPL == 4) {
            uint2 hv = *(const uint2*)hp;
            acc[0] += w * __uint_as_float(hv.x << 16);
            acc[1] += w * __uint_as_float(hv.x & 0xffff0000u);
            acc[2] += w * __uint_as_float(hv.y << 16);
            acc[3] += w * __uint_as_float(hv.y & 0xffff0000u);
        } else {
            unsigned int hv = *(const unsigned int*)hp;
            acc[0] += w * __uint_as_float(hv << 16);
            acc[1] += w * __uint_as_float(hv & 0xffff0000u);
        }
    }
    float invz = 1.f / z;
    #pragma unroll
    for (int j = 0; j < VPL; j++)
        out[(long)dst * F + lane * VPL + j] = acc[j] * invz + bias[lane * VPL + j];
}

// ---------------- batchnorm ----------------
template <int F>
__global__ void k_bnstats(const float* __restrict__ x, float* bnsum, float* bnsq, int n) {
    int t = threadIdx.x;  // blockDim == F
    float s = 0.f, q = 0.f;
    for (int r = blockIdx.x; r < n; r += gridDim.x) {
        float v = x[(long)r * F + t];
        s += v; q += v * v;
    }
    atomicAdd(&bnsum[t], s);
    atomicAdd(&bnsq[t], q);
}

// normalize + ReLU, emit bf16 (next GEMM's A operand / pool input)
template <int F>
__global__ void k_bnapply(const float* __restrict__ x, unsigned short* __restrict__ y,
                          const float* __restrict__ bnsum, const float* __restrict__ bnsq,
                          const float* __restrict__ gamma, const float* __restrict__ beta,
                          int n) {
    int idx = blockIdx.x * blockDim.x + threadIdx.x;
    if (idx >= n * F) return;
    int f = idx & (F - 1);
    float invN = 1.f / (float)n;
    float mu = bnsum[f] * invN;
    float var = bnsq[f] * invN - mu * mu;
    float v = (x[idx] - mu) * rsqrtf(var + EPSBN) * gamma[f] + beta[f];
    y[idx] = f2b_rne(v > 0.f ? v : 0.f);
}

// ---------------- graph mean-pool: batch is SORTED -> segmented reduction ----------------
static __device__ __forceinline__ int lower_bound_i(const int* __restrict__ a, int n, int v) {
    int lo = 0, hi = n;
    while (lo < hi) { int mid = (lo + hi) >> 1; if (a[mid] < v) lo = mid + 1; else hi = mid; }
    return lo;
}

// grid = G * POOL_SPLIT blocks, 256 threads. One atomicAdd per (block, feature).
__global__ __launch_bounds__(256) void k_pool2(const unsigned short* __restrict__ x,
                                               const int* __restrict__ batch,
                                               float* __restrict__ featsum,
                                               int* __restrict__ gcnt, int n) {
    __shared__ float sm[256];
    int g = blockIdx.x / POOL_SPLIT;
    int part = blockIdx.x % POOL_SPLIT;
    int t = threadIdx.x;
    int lo = lower_bound_i(batch, n, g);
    int hi = lower_bound_i(batch, n, g + 1);
    int f = t & 127;
    int phase = t >> 7;  // 0/1: two rows in flight
    float acc = 0.f;
    for (int r = lo + part * 2 + phase; r < hi; r += POOL_SPLIT * 2)
        acc += u2f(x[(long)r * 128 + f]);
    sm[t] = acc;
    __syncthreads();
    if (t < 128) {
        float s = sm[t] + sm[t + 128];
        atomicAdd(&featsum[g * 128 + t], s);
    }
    if (t == 0 && part == 0) gcnt[g] = hi - lo;
}

// ---------------- heads ----------------
__global__ void k_head(const float* __restrict__ featsum, const int* __restrict__ gcnt,
                       const float* __restrict__ clfW, const float* __restrict__ clfb,
                       const float* __restrict__ dW1, const float* __restrict__ db1,
                       const float* __restrict__ dW2, const float* __restrict__ db2,
                       void* __restrict__ out, const int* flagcnt, int G) {
    __shared__ float feat[128];
    __shared__ float dh[64];
    bool f32o = is_f32(flagcnt);
    float* of = (float*)out;
    __hip_bfloat16* ob = (__hip_bfloat16*)out;
    int g = blockIdx.x, t = threadIdx.x;  // 128 threads
    float c = fmaxf((float)gcnt[g], 1.f);
    float fv = featsum[g * 128 + t] / c;
    feat[t] = fv;
    int fidx = G * 10 + G * 2 + g * 128 + t;
    if (f32o) of[fidx] = fv; else ob[fidx] = __float2bfloat16(fv);
    __syncthreads();
    if (t < 10) {
        float a = clfb[t];
        for (int k = 0; k < 128; k++) a += feat[k] * clfW[k * 10 + t];
        int idx = g * 10 + t;
        if (f32o) of[idx] = a; else ob[idx] = __float2bfloat16(a);
    }
    if (t < 64) {
        float a = db1[t];
        for (int k = 0; k < 128; k++) a += feat[k] * dW1[k * 64 + t];
        dh[t] = a > 0.f ? a : 0.f;
    }
    __syncthreads();
    if (t < 2) {
        float a = db2[t];
        for (int k = 0; k < 64; k++) a += dh[k] * dW2[k * 2 + t];
        int idx = G * 10 + g * 2 + t;
        if (f32o) of[idx] = a; else ob[idx] = __float2bfloat16(a);
    }
}

// ---------------- launch ----------------
extern "C" void kernel_launch(void* const* d_in, const int* in_sizes, int n_in,
                              void* d_out, int out_size, void* d_ws, size_t ws_size,
                              hipStream_t stream) {
    const void* x_in = d_in[0];
    const int* ei    = (const int*)d_in[1];
    const int* batch = (const int*)d_in[2];
    const int N = in_sizes[2];
    const int E = in_sizes[1] / 2;
    const int G = 64;

    // workspace layout (256B aligned chunks)
    char* ws = (char*)d_ws;
    size_t off = 0;
    auto alloc = [&](size_t bytes) {
        void* p = ws + off;
        off += (bytes + 255) & ~(size_t)255;
        return p;
    };
    int*   flagcnt = (int*)alloc(256);
    int*   cnt     = (int*)alloc((size_t)N * 4);
    int*   adj     = (int*)alloc((size_t)N * CAP * 4);
    float* xbuf    = (float*)alloc((size_t)N * 256 * 4);           // fp32 agg output
    unsigned short* hbuf = (unsigned short*)alloc((size_t)N * 256 * 2);  // bf16 h
    unsigned short* xb16 = (unsigned short*)alloc((size_t)N * 256 * 2);  // bf16 x (GEMM A)
    unsigned short* Wt0  = (unsigned short*)alloc((size_t)256 * 128 * 2);
    unsigned short* Wt1  = (unsigned short*)alloc((size_t)256 * 256 * 2);
    unsigned short* Wt2  = (unsigned short*)alloc((size_t)128 * 256 * 2);
    float* es      = (float*)alloc((size_t)N * 4 * 4);
    float* ed      = (float*)alloc((size_t)N * 4 * 4);
    float* bnsum   = (float*)alloc(256 * 4 + 256 * 4);
    float* bnsq    = bnsum + 256;
    float* featsum = (float*)alloc((size_t)G * 128 * 4 + (size_t)G * 4);
    int*   gcnt    = (int*)(featsum + G * 128);

    // fp32 copies of the 24 float param tensors (d_in[3..26])
    CvtTab tab;
    float* pp[NPARAM];
    int ptot = 0;
    for (int j = 0; j < NPARAM; j++) {
        int cnt_j = in_sizes[3 + j];
        pp[j] = (float*)alloc((size_t)cnt_j * 4);
        tab.src[j] = d_in[3 + j];
        tab.dst[j] = pp[j];
        tab.off[j] = ptot;
        ptot += cnt_j;
    }
    tab.off[NPARAM] = ptot;
    float *Wf0 = pp[0], *asf0 = pp[1], *adf0 = pp[2], *bf0 = pp[3], *gf0 = pp[4], *bef0 = pp[5];
    float *Wf1 = pp[6], *asf1 = pp[7], *adf1 = pp[8], *bf1 = pp[9], *gf1 = pp[10], *bef1 = pp[11];
    float *Wf2 = pp[12], *asf2 = pp[13], *adf2 = pp[14], *bf2 = pp[15], *gf2 = pp[16], *bef2 = pp[17];
    float *clfWf = pp[18], *clfbf = pp[19], *dW1f = pp[20], *db1f = pp[21], *dW2f = pp[22], *db2f = pp[23];

    const int TPB = 256;
    int wgrid = (N + 3) / 4;  // one wave per node
    int mblocks = (N + 63) / 64;

    // dtype probe + converts
    hipMemsetAsync(flagcnt, 0, 4, stream);
    k_detect<<<1, 256, 0, stream>>>((const unsigned short*)x_in, flagcnt);
    k_cvt_xb<<<(N * 128 + TPB - 1) / TPB, TPB, 0, stream>>>(x_in, xb16, flagcnt, N * 128);
    k_cvt_params<<<(ptot + TPB - 1) / TPB, TPB, 0, stream>>>(tab, flagcnt, ptot);
    k_transW<<<(128 * 256 + TPB - 1) / TPB, TPB, 0, stream>>>(Wf0, Wt0, 128, 256);
    k_transW<<<(256 * 256 + TPB - 1) / TPB, TPB, 0, stream>>>(Wf1, Wt1, 256, 256);
    k_transW<<<(256 * 128 + TPB - 1) / TPB, TPB, 0, stream>>>(Wf2, Wt2, 256, 128);

    // graph build
    k_init_graph<<<(N + TPB - 1) / TPB, TPB, 0, stream>>>(cnt, adj, N);
    k_fill_graph<<<(E + TPB - 1) / TPB, TPB, 0, stream>>>(ei, cnt, adj, E);

    // ---- layer 0: K=128 -> F=256, H=4, D=64 ----
    {
        k_gemm_mfma<<<dim3(mblocks, 4), 256, 0, stream>>>(xb16, Wt0, hbuf, N, 128, 256);
        k_attn<256, 4><<<wgrid, 256, 0, stream>>>(hbuf, asf0, adf0, es, ed, N);
        k_agg<256, 4><<<wgrid, 256, 0, stream>>>(hbuf, es, ed, cnt, adj, bf0, xbuf, N);
        hipMemsetAsync(bnsum, 0, 2048, stream);
        k_bnstats<256><<<160, 256, 0, stream>>>(xbuf, bnsum, bnsq, N);
        k_bnapply<256><<<(N * 256 + TPB - 1) / TPB, TPB, 0, stream>>>(xbuf, xb16, bnsum, bnsq, gf0, bef0, N);
    }
    // ---- layer 1: K=256 -> F=256, H=4, D=64 ----
    {
        k_gemm_mfma<<<dim3(mblocks, 4), 256, 0, stream>>>(xb16, Wt1, hbuf, N, 256, 256);
        k_attn<256, 4><<<wgrid, 256, 0, stream>>>(hbuf, asf1, adf1, es, ed, N);
        k_agg<256, 4><<<wgrid, 256, 0, stream>>>(hbuf, es, ed, cnt, adj, bf1, xbuf, N);
        hipMemsetAsync(bnsum, 0, 2048, stream);
        k_bnstats<256><<<160, 256, 0, stream>>>(xbuf, bnsum, bnsq, N);
        k_bnapply<256><<<(N * 256 + TPB - 1) / TPB, TPB, 0, stream>>>(xbuf, xb16, bnsum, bnsq, gf1, bef1, N);
    }
    // ---- layer 2: K=256 -> F=128, H=1, D=128 ----
    {
        k_gemm_mfma<<<dim3(mblocks, 2), 256, 0, stream>>>(xb16, Wt2, hbuf, N, 256, 128);
        k_attn<128, 1><<<wgrid, 256, 0, stream>>>(hbuf, asf2, adf2, es, ed, N);
        k_agg<128, 1><<<wgrid, 256, 0, stream>>>(hbuf, es, ed, cnt, adj, bf2, xbuf, N);
        hipMemsetAsync(bnsum, 0, 2048, stream);
        k_bnstats<128><<<160, 128, 0, stream>>>(xbuf, bnsum, bnsq, N);
        k_bnapply<128><<<(N * 128 + TPB - 1) / TPB, TPB, 0, stream>>>(xbuf, xb16, bnsum, bnsq, gf2, bef2, N);
    }

    // ---- pooling + heads ----
    hipMemsetAsync(featsum, 0, (size_t)G * 128 * 4 + (size_t)G * 4, stream);
    k_pool2<<<G * POOL_SPLIT, 256, 0, stream>>>(xb16, batch, featsum, gcnt, N);
    k_head<<<G, 128, 0, stream>>>(featsum, gcnt, clfWf, clfbf, dW1f, db1f, dW2f, db2f,
                                  d_out, flagcnt, G);
}